// Round 12
// baseline (562.658 us; speedup 1.0000x reference)
//
#include <hip/hip_runtime.h>

#define NB 2
#define D 32
#define H 128
#define NSTEPS 8
#define BT 256

typedef _Float16 f16;
typedef _Float16 f16x2 __attribute__((ext_vector_type(2)));
typedef _Float16 f16x8 __attribute__((ext_vector_type(8)));
typedef float    f32x4 __attribute__((ext_vector_type(4)));
typedef unsigned int uint;
typedef uint uintx4 __attribute__((ext_vector_type(4)));

// Weights/biases feeding a tanh are pre-scaled by 2*log2(e) at staging time, so
// the MFMA accumulator is already v = 2*log2e*z and tanh needs no multiply:
#define TSCL 2.8853900817779268f

__device__ __forceinline__ float fast_tanh_pre(float v) {
    // v = 2*log2e*z. tanh(z) = 1 - 2/(1+2^v); exp2 saturates -> exact +-1 limits.
    float e = __builtin_amdgcn_exp2f(v);
    return 1.f - 2.f * __builtin_amdgcn_rcpf(1.f + e);
}
__device__ __forceinline__ uint tanh_pk(float a, float b) {
    return __builtin_bit_cast(uint, __builtin_amdgcn_cvt_pkrtz(fast_tanh_pre(a), fast_tanh_pre(b)));
}
__device__ __forceinline__ uint pku(float a, float b) {
    return __builtin_bit_cast(uint, __builtin_amdgcn_cvt_pkrtz(a, b));
}
__device__ __forceinline__ float lo32(uint u) { return (float)__builtin_bit_cast(f16x2, u)[0]; }
__device__ __forceinline__ float hi32(uint u) { return (float)__builtin_bit_cast(f16x2, u)[1]; }

__device__ const float CC[6] = {0.f, 0.2f, 0.3f, 0.8f, 8.f/9.f, 1.f};

// BOTTLENECK MODEL (R0..R21 measured):
//  * LADDER: 747 (base) -> 710 (dual-sample ILP) -> 660 (L2/L3 fusion, direct
//    B-frags) -> 552/576 (R21: k1..k3 history -> LDS stash; spill ELIMINATED:
//    WRITE = exactly 8.2 MB output, FETCH = 5 MB weights, VGPR=128 fits).
//  * Issue model @R21 (5160 VALU-busy cyc/wave-stage): tanh ~2700 (128 tanh x
//    {exp2 8cy, add, rcp 8cy, fma} — irreducible: LUT R14 failed, batched-rcp
//    R19 failed, trans is ~8cyc), DOPRI/ci/pack ~500, ~2000 codegen overhead.
//    VALU 72% + MFMA 24% co-issue; ~28% VALU idle = dependency stalls at
//    2 waves/SIMD.
//  * Occupancy is CLOSED: 3 blocks/CU needs LDS<=53.3KB but W2f(32K)+KS(24.5K)
//    alone exceed it; 3 samples/thread re-spills the 128-reg granule.
//  * THIS ROUND (T5): s_setprio(1) around MFMA regions, prio 0 during tanh.
//    Step loop has NO barriers -> the 2 waves/SIMD drift into diverse phases;
//    priority biases the arbiter to issue wave B's MFMAs under wave A's tanh
//    stalls (anti-aligns pipe demand). Attn-analog measured +4-7%; lockstep
//    GEMM null. Null here (±1%) => scheduler already optimal, pivot to
//    packed-f16 DOPRI.
struct __align__(16) SMem {
    f16   W1f[8 * 64 * 8];     // [nt][lane][j]      : TSCL*W1[32+phi1(q,j)][nt*16+mr]
    f16   W2f[8 * 4 * 64 * 8]; // [nt][kt][lane][j]  : TSCL*W2[phi(kt,q,j)][nt*16+mr]
    f16   W3f[2 * 4 * 64 * 8]; // [nt][kt][lane][j]  : W3[phi(kt,q,j)][nt*16+mr] (unscaled)
    float B1[H], S1[H], B2[H], B3[D];   // B1,S1,B2 pre-scaled by TSCL
    uint  KS[3][2][4][BT];     // k1..k3 history stash [k-idx][sample][j][tid]
                               // lane-stride 4B -> conflict-free; private per
                               // thread -> NO barrier needed.
};

// phi(kt,q,j) = (2kt + j/4)*16 + q*4 + j%4 ; phi1(q,j) = (j/4)*16 + q*4 + j%4.
// Identical k-permutation on A (staged weights) and B (C-layout activations)
// -> MFMA k-sum invariant. Zero activation LDS traffic, zero shuffles.
//
// REGISTER MODEL (measured R3..R21):
//  * min-waves=2 (any spelling) -> VGPR=128; with the KS stash the working
//    set now FITS (zero spill). min-waves=1 -> 168 regs but 1 block/CU. Keep
//    flat_work_group_size(256,256) + waves_per_eu(2,2).
//  * Inner weight loops stay at unroll<=2 / unroll 1 (R4/R7: full unroll
//    -> GB-scale spill). Register arrays indexed only by unrolled vars.

__global__
__attribute__((amdgpu_flat_work_group_size(256, 256), amdgpu_waves_per_eu(2, 2)))
void ffjord_mfma(
    const float* __restrict__ x_in,
    const float* __restrict__ W1, const float* __restrict__ b1,
    const float* __restrict__ W2, const float* __restrict__ b2,
    const float* __restrict__ W3, const float* __restrict__ b3,
    float* __restrict__ out)
{
    __shared__ SMem sm;

    const int tid  = threadIdx.x;
    const int lane = tid & 63;
    const int mrow = lane & 15;      // my sample within the wave tile
    const int quad = lane >> 4;      // k/feature quad
    const int wid  = tid >> 6;
    // Two samples per thread: A and B tiles are independent 16-sample MFMA
    // B-fragments sharing every weight fragment / C-init.
    const int sidxA = blockIdx.x * 128 + wid * 32 + mrow;
    const int sidxB = sidxA + 16;

    float xA[8], xB[8];
    uint  k3A[4], k4A[4], k3B[4], k4B[4];   // k4,k5 history (hot, registers)
    uint  byA[4], byB[4];

    #pragma unroll
    for (int nt = 0; nt < 2; ++nt) {
        f32x4 va = *(const f32x4*)(x_in + (size_t)sidxA*D + nt*16 + quad*4);
        f32x4 vb = *(const f32x4*)(x_in + (size_t)sidxB*D + nt*16 + quad*4);
        #pragma unroll
        for (int r = 0; r < 4; ++r) { xA[nt*4 + r] = va[r]; xB[nt*4 + r] = vb[r]; }
    }

    const float dt = 0.125f;

    for (int bij = 0; bij < NB; ++bij) {
        const float* W1b = W1 + (size_t)bij * 2*D*H;
        const float* b1b = b1 + bij*H;
        const float* W2b = W2 + (size_t)bij * H*H;
        const float* b2b = b2 + bij*H;
        const float* W3b = W3 + (size_t)bij * H*D;
        const float* b3b = b3 + bij*D;

        __syncthreads();  // prior bijector done reading weights
        // ---- stage weights: fragment-order, k-permuted, f16, tanh-prescaled ----
        #pragma unroll 1
        for (int g = tid; g < 8*64; g += BT) {               // W1f (x TSCL)
            int nt = g >> 6, ln = g & 63, q = (ln >> 4) & 3, mr = ln & 15;
            f16 tmp[8];
            #pragma unroll
            for (int j = 0; j < 8; ++j) {
                int feat = ((j >> 2) << 4) + q*4 + (j & 3);  // phi1
                tmp[j] = (f16)(W1b[(size_t)(D + feat)*H + nt*16 + mr] * TSCL);
            }
            *(f16x8*)&sm.W1f[(size_t)g * 8] = *(f16x8*)tmp;
        }
        #pragma unroll 1
        for (int g = tid; g < 8*4*64; g += BT) {             // W2f (x TSCL)
            int nt = g >> 8, kt = (g >> 6) & 3, ln = g & 63, q = (ln >> 4) & 3, mr = ln & 15;
            f16 tmp[8];
            #pragma unroll
            for (int j = 0; j < 8; ++j) {
                int feat = (2*kt + (j >> 2))*16 + q*4 + (j & 3);  // phi
                tmp[j] = (f16)(W2b[(size_t)feat*H + nt*16 + mr] * TSCL);
            }
            *(f16x8*)&sm.W2f[(size_t)g * 8] = *(f16x8*)tmp;
        }
        #pragma unroll 1
        for (int g = tid; g < 2*4*64; g += BT) {             // W3f (unscaled)
            int nt = g >> 8, kt = (g >> 6) & 3, ln = g & 63, q = (ln >> 4) & 3, mr = ln & 15;
            f16 tmp[8];
            #pragma unroll
            for (int j = 0; j < 8; ++j) {
                int feat = (2*kt + (j >> 2))*16 + q*4 + (j & 3);  // phi
                tmp[j] = (f16)W3b[(size_t)feat*D + nt*16 + mr];
            }
            *(f16x8*)&sm.W3f[(size_t)g * 8] = *(f16x8*)tmp;
        }
        #pragma unroll 1
        for (int n = tid; n < H; n += BT) {                  // biases + t-fold sums (x TSCL)
            float s = 0.f;
            for (int i = 0; i < D; ++i) s += W1b[(size_t)i*H + n];
            sm.S1[n] = s * TSCL; sm.B1[n] = b1b[n] * TSCL; sm.B2[n] = b2b[n] * TSCL;
        }
        if (tid < D) sm.B3[tid] = b3b[tid];
        __syncthreads();

        // y := x  (packed)
        #pragma unroll
        for (int p = 0; p < 4; ++p) {
            byA[p] = pku(xA[2*p], xA[2*p + 1]);
            byB[p] = pku(xB[2*p], xB[2*p + 1]);
        }

        for (int step = 0; step < NSTEPS; ++step) {
            const float t0 = step * dt;
            #pragma unroll 1
            for (int s = 0; s < 6; ++s) {
                const float te = t0 + dt * CC[s];

                // ======== EVAL: two samples share every weight fragment ========
                // layer 1 (K=32): C init = (b1 + te*S1)*TSCL. Output built
                // DIRECTLY as the 4 L2 B-fragments (frag ktg = L1 nt 2ktg,2ktg+1).
                f16x8 fA1[4], fB1[4];
                {
                    union { f16x8 v; uint u[4]; } ba, bb;
                    ba.u[0] = byA[0]; ba.u[1] = byA[1]; ba.u[2] = byA[2]; ba.u[3] = byA[3];
                    bb.u[0] = byB[0]; bb.u[1] = byB[1]; bb.u[2] = byB[2]; bb.u[3] = byB[3];
                    #pragma unroll
                    for (int ktg = 0; ktg < 4; ++ktg) {
                        uint da[4], db[4];
                        #pragma unroll
                        for (int h = 0; h < 2; ++h) {
                            const int nt = ktg*2 + h;
                            __builtin_amdgcn_s_setprio(1);   // MFMA region: preempt tanh-phase waves
                            f16x8 wf = *(const f16x8*)&sm.W1f[(nt*64 + lane)*8];
                            f32x4 bv = *(const f32x4*)&sm.B1[nt*16 + quad*4];
                            f32x4 sv = *(const f32x4*)&sm.S1[nt*16 + quad*4];
                            f32x4 ci;
                            #pragma unroll
                            for (int r = 0; r < 4; ++r) ci[r] = fmaf(te, sv[r], bv[r]);
                            f32x4 accA = __builtin_amdgcn_mfma_f32_16x16x32_f16(wf, ba.v, ci, 0, 0, 0);
                            f32x4 accB = __builtin_amdgcn_mfma_f32_16x16x32_f16(wf, bb.v, ci, 0, 0, 0);
                            __builtin_amdgcn_s_setprio(0);   // tanh region: yield to MFMA-phase waves
                            da[h*2+0] = tanh_pk(accA[0], accA[1]);
                            da[h*2+1] = tanh_pk(accA[2], accA[3]);
                            db[h*2+0] = tanh_pk(accB[0], accB[1]);
                            db[h*2+1] = tanh_pk(accB[2], accB[3]);
                        }
                        uintx4 ua = {da[0], da[1], da[2], da[3]};
                        uintx4 ub = {db[0], db[1], db[2], db[3]};
                        fA1[ktg] = __builtin_bit_cast(f16x8, ua);
                        fB1[ktg] = __builtin_bit_cast(f16x8, ub);
                    }
                }
                // layer 2 (K=128) with layer 3 FUSED: each completed ph2
                // fragment (per ktg) feeds its 4 L3 MFMAs immediately and dies.
                float kdA[8], kdB[8];
                {
                    f32x4 a3A[2], a3B[2];
                    #pragma unroll
                    for (int n3 = 0; n3 < 2; ++n3) {
                        f32x4 c = *(const f32x4*)&sm.B3[n3*16 + quad*4];
                        a3A[n3] = c; a3B[n3] = c;
                    }
                    #pragma unroll 1
                    for (int ktg = 0; ktg < 4; ++ktg) {
                        uint da[4], db[4];
                        #pragma unroll
                        for (int h = 0; h < 2; ++h) {
                            const int nt = ktg*2 + h;
                            __builtin_amdgcn_s_setprio(1);   // 8-MFMA cluster
                            f32x4 c0 = *(const f32x4*)&sm.B2[nt*16 + quad*4];
                            f32x4 accA = c0, accB = c0;
                            #pragma unroll
                            for (int kt2 = 0; kt2 < 4; ++kt2) {
                                f16x8 wf = *(const f16x8*)&sm.W2f[((nt*4 + kt2)*64 + lane)*8];
                                accA = __builtin_amdgcn_mfma_f32_16x16x32_f16(wf, fA1[kt2], accA, 0, 0, 0);
                                accB = __builtin_amdgcn_mfma_f32_16x16x32_f16(wf, fB1[kt2], accB, 0, 0, 0);
                            }
                            __builtin_amdgcn_s_setprio(0);   // tanh region
                            da[h*2+0] = tanh_pk(accA[0], accA[1]);
                            da[h*2+1] = tanh_pk(accA[2], accA[3]);
                            db[h*2+0] = tanh_pk(accB[0], accB[1]);
                            db[h*2+1] = tanh_pk(accB[2], accB[3]);
                        }
                        uintx4 ua = {da[0], da[1], da[2], da[3]};
                        uintx4 ub = {db[0], db[1], db[2], db[3]};
                        f16x8 fra = __builtin_bit_cast(f16x8, ua);
                        f16x8 frb = __builtin_bit_cast(f16x8, ub);
                        __builtin_amdgcn_s_setprio(1);       // L3 4-MFMA cluster
                        #pragma unroll
                        for (int n3 = 0; n3 < 2; ++n3) {
                            f16x8 wf3 = *(const f16x8*)&sm.W3f[((n3*4 + ktg)*64 + lane)*8];
                            a3A[n3] = __builtin_amdgcn_mfma_f32_16x16x32_f16(wf3, fra, a3A[n3], 0, 0, 0);
                            a3B[n3] = __builtin_amdgcn_mfma_f32_16x16x32_f16(wf3, frb, a3B[n3], 0, 0, 0);
                        }
                        __builtin_amdgcn_s_setprio(0);
                    }
                    #pragma unroll
                    for (int n3 = 0; n3 < 2; ++n3)
                        #pragma unroll
                        for (int r = 0; r < 4; ++r) {
                            kdA[n3*4 + r] = a3A[n3][r];
                            kdB[n3*4 + r] = a3B[n3][r];
                        }
                }

                // ===== DOPRI combine; k1..k3 history in LDS stash, k4/k5 in
                // registers. Each thread touches only its own stash slots. =====
                switch (s) {
                case 0:
                    #pragma unroll
                    for (int j = 0; j < 4; ++j) {
                        sm.KS[0][0][j][tid] = pku(kdA[2*j], kdA[2*j+1]);
                        byA[j] = pku(fmaf(dt*0.2f, kdA[2*j],   xA[2*j]),
                                     fmaf(dt*0.2f, kdA[2*j+1], xA[2*j+1]));
                        sm.KS[0][1][j][tid] = pku(kdB[2*j], kdB[2*j+1]);
                        byB[j] = pku(fmaf(dt*0.2f, kdB[2*j],   xB[2*j]),
                                     fmaf(dt*0.2f, kdB[2*j+1], xB[2*j+1]));
                    }
                    break;
                case 1:
                    #pragma unroll
                    for (int j = 0; j < 4; ++j) {
                        uint a0 = sm.KS[0][0][j][tid];
                        sm.KS[1][0][j][tid] = pku(kdA[2*j], kdA[2*j+1]);
                        byA[j] = pku(xA[2*j]   + dt*((3.f/40.f)*lo32(a0) + (9.f/40.f)*kdA[2*j]),
                                     xA[2*j+1] + dt*((3.f/40.f)*hi32(a0) + (9.f/40.f)*kdA[2*j+1]));
                        uint b0 = sm.KS[0][1][j][tid];
                        sm.KS[1][1][j][tid] = pku(kdB[2*j], kdB[2*j+1]);
                        byB[j] = pku(xB[2*j]   + dt*((3.f/40.f)*lo32(b0) + (9.f/40.f)*kdB[2*j]),
                                     xB[2*j+1] + dt*((3.f/40.f)*hi32(b0) + (9.f/40.f)*kdB[2*j+1]));
                    }
                    break;
                case 2:
                    #pragma unroll
                    for (int j = 0; j < 4; ++j) {
                        uint a0 = sm.KS[0][0][j][tid], a1 = sm.KS[1][0][j][tid];
                        sm.KS[2][0][j][tid] = pku(kdA[2*j], kdA[2*j+1]);
                        byA[j] = pku(xA[2*j]   + dt*((44.f/45.f)*lo32(a0) - (56.f/15.f)*lo32(a1) + (32.f/9.f)*kdA[2*j]),
                                     xA[2*j+1] + dt*((44.f/45.f)*hi32(a0) - (56.f/15.f)*hi32(a1) + (32.f/9.f)*kdA[2*j+1]));
                        uint b0 = sm.KS[0][1][j][tid], b1 = sm.KS[1][1][j][tid];
                        sm.KS[2][1][j][tid] = pku(kdB[2*j], kdB[2*j+1]);
                        byB[j] = pku(xB[2*j]   + dt*((44.f/45.f)*lo32(b0) - (56.f/15.f)*lo32(b1) + (32.f/9.f)*kdB[2*j]),
                                     xB[2*j+1] + dt*((44.f/45.f)*hi32(b0) - (56.f/15.f)*hi32(b1) + (32.f/9.f)*kdB[2*j+1]));
                    }
                    break;
                case 3:
                    #pragma unroll
                    for (int j = 0; j < 4; ++j) {
                        uint a0 = sm.KS[0][0][j][tid], a1 = sm.KS[1][0][j][tid], a2 = sm.KS[2][0][j][tid];
                        k3A[j] = pku(kdA[2*j], kdA[2*j+1]);
                        byA[j] = pku(xA[2*j]   + dt*((19372.f/6561.f)*lo32(a0) - (25360.f/2187.f)*lo32(a1)
                                                   + (64448.f/6561.f)*lo32(a2) - (212.f/729.f)*kdA[2*j]),
                                     xA[2*j+1] + dt*((19372.f/6561.f)*hi32(a0) - (25360.f/2187.f)*hi32(a1)
                                                   + (64448.f/6561.f)*hi32(a2) - (212.f/729.f)*kdA[2*j+1]));
                        uint b0 = sm.KS[0][1][j][tid], b1 = sm.KS[1][1][j][tid], b2 = sm.KS[2][1][j][tid];
                        k3B[j] = pku(kdB[2*j], kdB[2*j+1]);
                        byB[j] = pku(xB[2*j]   + dt*((19372.f/6561.f)*lo32(b0) - (25360.f/2187.f)*lo32(b1)
                                                   + (64448.f/6561.f)*lo32(b2) - (212.f/729.f)*kdB[2*j]),
                                     xB[2*j+1] + dt*((19372.f/6561.f)*hi32(b0) - (25360.f/2187.f)*hi32(b1)
                                                   + (64448.f/6561.f)*hi32(b2) - (212.f/729.f)*kdB[2*j+1]));
                    }
                    break;
                case 4:
                    #pragma unroll
                    for (int j = 0; j < 4; ++j) {
                        uint a0 = sm.KS[0][0][j][tid], a1 = sm.KS[1][0][j][tid], a2 = sm.KS[2][0][j][tid];
                        k4A[j] = pku(kdA[2*j], kdA[2*j+1]);
                        byA[j] = pku(xA[2*j]   + dt*((9017.f/3168.f)*lo32(a0) - (355.f/33.f)*lo32(a1)
                                                   + (46732.f/5247.f)*lo32(a2) + (49.f/176.f)*lo32(k3A[j])
                                                   - (5103.f/18656.f)*kdA[2*j]),
                                     xA[2*j+1] + dt*((9017.f/3168.f)*hi32(a0) - (355.f/33.f)*hi32(a1)
                                                   + (46732.f/5247.f)*hi32(a2) + (49.f/176.f)*hi32(k3A[j])
                                                   - (5103.f/18656.f)*kdA[2*j+1]));
                        uint b0 = sm.KS[0][1][j][tid], b1 = sm.KS[1][1][j][tid], b2 = sm.KS[2][1][j][tid];
                        k4B[j] = pku(kdB[2*j], kdB[2*j+1]);
                        byB[j] = pku(xB[2*j]   + dt*((9017.f/3168.f)*lo32(b0) - (355.f/33.f)*lo32(b1)
                                                   + (46732.f/5247.f)*lo32(b2) + (49.f/176.f)*lo32(k3B[j])
                                                   - (5103.f/18656.f)*kdB[2*j]),
                                     xB[2*j+1] + dt*((9017.f/3168.f)*hi32(b0) - (355.f/33.f)*hi32(b1)
                                                   + (46732.f/5247.f)*hi32(b2) + (49.f/176.f)*hi32(k3B[j])
                                                   - (5103.f/18656.f)*kdB[2*j+1]));
                    }
                    break;
                default:
                    #pragma unroll
                    for (int j = 0; j < 4; ++j) {
                        uint a0 = sm.KS[0][0][j][tid], a2 = sm.KS[2][0][j][tid];
                        float xa = xA[2*j]   + dt*((35.f/384.f)*lo32(a0) + (500.f/1113.f)*lo32(a2)
                                                 + (125.f/192.f)*lo32(k3A[j]) - (2187.f/6784.f)*lo32(k4A[j])
                                                 + (11.f/84.f)*kdA[2*j]);
                        float xb = xA[2*j+1] + dt*((35.f/384.f)*hi32(a0) + (500.f/1113.f)*hi32(a2)
                                                 + (125.f/192.f)*hi32(k3A[j]) - (2187.f/6784.f)*hi32(k4A[j])
                                                 + (11.f/84.f)*kdA[2*j+1]);
                        xA[2*j] = xa; xA[2*j+1] = xb;
                        byA[j] = pku(xa, xb);
                        uint b0 = sm.KS[0][1][j][tid], b2 = sm.KS[2][1][j][tid];
                        float xc = xB[2*j]   + dt*((35.f/384.f)*lo32(b0) + (500.f/1113.f)*lo32(b2)
                                                 + (125.f/192.f)*lo32(k3B[j]) - (2187.f/6784.f)*lo32(k4B[j])
                                                 + (11.f/84.f)*kdB[2*j]);
                        float xd = xB[2*j+1] + dt*((35.f/384.f)*hi32(b0) + (500.f/1113.f)*hi32(b2)
                                                 + (125.f/192.f)*hi32(k3B[j]) - (2187.f/6784.f)*hi32(k4B[j])
                                                 + (11.f/84.f)*kdB[2*j+1]);
                        xB[2*j] = xc; xB[2*j+1] = xd;
                        byB[j] = pku(xc, xd);
                    }
                    break;
                }
            } // stages
        } // steps
    } // bijectors

    #pragma unroll
    for (int nt = 0; nt < 2; ++nt) {
        f32x4 va, vb;
        #pragma unroll
        for (int r = 0; r < 4; ++r) { va[r] = xA[nt*4 + r]; vb[r] = xB[nt*4 + r]; }
        *(f32x4*)(out + (size_t)sidxA*D + nt*16 + quad*4) = va;
        *(f32x4*)(out + (size_t)sidxB*D + nt*16 + quad*4) = vb;
    }
}

extern "C" void kernel_launch(void* const* d_in, const int* in_sizes, int n_in,
                              void* d_out, int out_size, void* d_ws, size_t ws_size,
                              hipStream_t stream) {
    (void)d_ws; (void)ws_size; (void)n_in; (void)out_size;
    const float* x  = (const float*)d_in[0];
    const float* W1 = (const float*)d_in[1];
    const float* b1 = (const float*)d_in[2];
    const float* W2 = (const float*)d_in[3];
    const float* b2 = (const float*)d_in[4];
    const float* W3 = (const float*)d_in[5];
    const float* b3 = (const float*)d_in[6];
    float* out = (float*)d_out;

    const int n = in_sizes[0] / D;          // 65536 samples
    const int grid = n / 128;               // 512 blocks (128 samples each), exact
    ffjord_mfma<<<grid, BT, 0, stream>>>(x, W1, b1, W2, b2, W3, b3, out);
}

// Round 13
// 518.043 us; speedup vs baseline: 1.0861x; 1.0861x over previous
//
#include <hip/hip_runtime.h>

#define NB 2
#define D 32
#define H 128
#define NSTEPS 8
#define BT 256

typedef _Float16 f16;
typedef _Float16 f16x2 __attribute__((ext_vector_type(2)));
typedef _Float16 f16x8 __attribute__((ext_vector_type(8)));
typedef float    f32x4 __attribute__((ext_vector_type(4)));
typedef unsigned int uint;
typedef uint uintx4 __attribute__((ext_vector_type(4)));

// Weights/biases feeding a tanh are pre-scaled by 2*log2(e) at staging time, so
// the MFMA accumulator is already v = 2*log2e*z:  tanh(z) = 1 - 2*rcp(1+2^v).
#define TSCL 2.8853900817779268f

// AFFINE-FOLD (R23): the "1 - 2r" map is folded into the NEXT layer's weights
// (W' = -2W) and C-init (B' = b + colsum W). The eval passes r directly:
// r = rcp(1+2^v). Saves 1 fma per tanh (128/thread-stage ~= 5% of VALU issue).
// Saturation exact: v>>0 -> e=inf -> r=0 (h=+1); v<<0 -> e=0 -> r=1 (h=-1).
__device__ __forceinline__ float sig_r(float v) {
    float e = __builtin_amdgcn_exp2f(v);
    return __builtin_amdgcn_rcpf(1.f + e);
}
__device__ __forceinline__ uint sig_pk(float a, float b) {
    return __builtin_bit_cast(uint, __builtin_amdgcn_cvt_pkrtz(sig_r(a), sig_r(b)));
}
__device__ __forceinline__ uint pku(float a, float b) {
    return __builtin_bit_cast(uint, __builtin_amdgcn_cvt_pkrtz(a, b));
}
__device__ __forceinline__ float lo32(uint u) { return (float)__builtin_bit_cast(f16x2, u)[0]; }
__device__ __forceinline__ float hi32(uint u) { return (float)__builtin_bit_cast(f16x2, u)[1]; }

__device__ const float CC[6] = {0.f, 0.2f, 0.3f, 0.8f, 8.f/9.f, 1.f};

// BOTTLENECK MODEL (R0..R22 measured):
//  * LADDER: 747 -> 710 (dual-sample ILP) -> 660 (L2/L3 fusion) -> 552/576
//    (R21: k1..k3 -> LDS stash, spill ELIMINATED: WRITE = 8.2 MB output only).
//  * R22: s_setprio around MFMA regions REGRESSED (576->590 steady). 2
//    lockstep waves/SIMD have no role split for priority to arbitrate. Reverted.
//  * Issue model: ~5200 VALU-busy cyc/wave-stage; tanh chain (exp2, add, rcp,
//    fma, pack) dominates. LUT (R14) and batched-rcp (R19) both REGRESSED —
//    per-op trans cost is cheap (~8cy); op COUNT is the lever.
//  * THIS ROUND: affine-fold "1-2r" into next-layer weights (see sig_r above).
//    Deletes 128 v_fma/thread-stage. W2f=-2*TSCL*W2, B2=TSCL*(b2+colsumW2);
//    W3f=-2*W3, B3=b3+colsumW3. L1 untouched (input is state, not tanh out).
//  * Occupancy CLOSED: 3 blocks/CU impossible (W2f 32K + KS 24.5K > 53.3K);
//    3 samples/thread re-spills. min-waves=2 + KS stash = zero-spill point.
struct __align__(16) SMem {
    f16   W1f[8 * 64 * 8];     // [nt][lane][j]      : TSCL*W1[32+phi1(q,j)][nt*16+mr]
    f16   W2f[8 * 4 * 64 * 8]; // [nt][kt][lane][j]  : -2*TSCL*W2[phi(kt,q,j)][nt*16+mr]
    f16   W3f[2 * 4 * 64 * 8]; // [nt][kt][lane][j]  : -2*W3[phi(kt,q,j)][nt*16+mr]
    float B1[H], S1[H], B2[H], B3[D];   // B1,S1 x TSCL; B2=TSCL*(b2+colsumW2); B3=b3+colsumW3
    uint  KS[3][2][4][BT];     // k1..k3 history stash [k-idx][sample][j][tid]
                               // lane-stride 4B -> conflict-free; private per
                               // thread -> NO barrier needed.
};

// phi(kt,q,j) = (2kt + j/4)*16 + q*4 + j%4 ; phi1(q,j) = (j/4)*16 + q*4 + j%4.
// Identical k-permutation on A (staged weights) and B (C-layout activations)
// -> MFMA k-sum invariant. Zero activation LDS traffic, zero shuffles.
//
// REGISTER MODEL (measured R3..R22):
//  * min-waves=2 (any spelling) -> VGPR=128; with the KS stash the working
//    set FITS (zero spill). min-waves=1 -> 168 regs but 1 block/CU (870us).
//    Keep flat_work_group_size(256,256) + waves_per_eu(2,2).
//  * Inner weight loops stay at unroll<=2 / unroll 1 (R4/R7: full unroll
//    -> GB-scale spill). Register arrays indexed only by unrolled vars.

__global__
__attribute__((amdgpu_flat_work_group_size(256, 256), amdgpu_waves_per_eu(2, 2)))
void ffjord_mfma(
    const float* __restrict__ x_in,
    const float* __restrict__ W1, const float* __restrict__ b1,
    const float* __restrict__ W2, const float* __restrict__ b2,
    const float* __restrict__ W3, const float* __restrict__ b3,
    float* __restrict__ out)
{
    __shared__ SMem sm;

    const int tid  = threadIdx.x;
    const int lane = tid & 63;
    const int mrow = lane & 15;      // my sample within the wave tile
    const int quad = lane >> 4;      // k/feature quad
    const int wid  = tid >> 6;
    // Two samples per thread: A and B tiles are independent 16-sample MFMA
    // B-fragments sharing every weight fragment / C-init.
    const int sidxA = blockIdx.x * 128 + wid * 32 + mrow;
    const int sidxB = sidxA + 16;

    float xA[8], xB[8];
    uint  k3A[4], k4A[4], k3B[4], k4B[4];   // k4,k5 history (hot, registers)
    uint  byA[4], byB[4];

    #pragma unroll
    for (int nt = 0; nt < 2; ++nt) {
        f32x4 va = *(const f32x4*)(x_in + (size_t)sidxA*D + nt*16 + quad*4);
        f32x4 vb = *(const f32x4*)(x_in + (size_t)sidxB*D + nt*16 + quad*4);
        #pragma unroll
        for (int r = 0; r < 4; ++r) { xA[nt*4 + r] = va[r]; xB[nt*4 + r] = vb[r]; }
    }

    const float dt = 0.125f;

    for (int bij = 0; bij < NB; ++bij) {
        const float* W1b = W1 + (size_t)bij * 2*D*H;
        const float* b1b = b1 + bij*H;
        const float* W2b = W2 + (size_t)bij * H*H;
        const float* b2b = b2 + bij*H;
        const float* W3b = W3 + (size_t)bij * H*D;
        const float* b3b = b3 + bij*D;

        __syncthreads();  // prior bijector done reading weights
        // ---- stage weights: fragment-order, k-permuted, f16, prescaled ----
        #pragma unroll 1
        for (int g = tid; g < 8*64; g += BT) {               // W1f (x TSCL)
            int nt = g >> 6, ln = g & 63, q = (ln >> 4) & 3, mr = ln & 15;
            f16 tmp[8];
            #pragma unroll
            for (int j = 0; j < 8; ++j) {
                int feat = ((j >> 2) << 4) + q*4 + (j & 3);  // phi1
                tmp[j] = (f16)(W1b[(size_t)(D + feat)*H + nt*16 + mr] * TSCL);
            }
            *(f16x8*)&sm.W1f[(size_t)g * 8] = *(f16x8*)tmp;
        }
        #pragma unroll 1
        for (int g = tid; g < 8*4*64; g += BT) {             // W2f (x -2*TSCL, affine-fold)
            int nt = g >> 8, kt = (g >> 6) & 3, ln = g & 63, q = (ln >> 4) & 3, mr = ln & 15;
            f16 tmp[8];
            #pragma unroll
            for (int j = 0; j < 8; ++j) {
                int feat = (2*kt + (j >> 2))*16 + q*4 + (j & 3);  // phi
                tmp[j] = (f16)(W2b[(size_t)feat*H + nt*16 + mr] * (-2.f * TSCL));
            }
            *(f16x8*)&sm.W2f[(size_t)g * 8] = *(f16x8*)tmp;
        }
        #pragma unroll 1
        for (int g = tid; g < 2*4*64; g += BT) {             // W3f (x -2, affine-fold)
            int nt = g >> 8, kt = (g >> 6) & 3, ln = g & 63, q = (ln >> 4) & 3, mr = ln & 15;
            f16 tmp[8];
            #pragma unroll
            for (int j = 0; j < 8; ++j) {
                int feat = (2*kt + (j >> 2))*16 + q*4 + (j & 3);  // phi
                tmp[j] = (f16)(W3b[(size_t)feat*D + nt*16 + mr] * -2.f);
            }
            *(f16x8*)&sm.W3f[(size_t)g * 8] = *(f16x8*)tmp;
        }
        #pragma unroll 1
        for (int n = tid; n < H; n += BT) {                  // biases + fold sums
            float s = 0.f;                                   // t-concat fold (x TSCL)
            for (int i = 0; i < D; ++i) s += W1b[(size_t)i*H + n];
            float s2 = 0.f;                                  // affine-fold colsum W2
            for (int k = 0; k < H; ++k) s2 += W2b[(size_t)k*H + n];
            sm.S1[n] = s * TSCL;
            sm.B1[n] = b1b[n] * TSCL;
            sm.B2[n] = (b2b[n] + s2) * TSCL;
        }
        if (tid < D) {                                       // affine-fold colsum W3
            float s3 = 0.f;
            for (int k = 0; k < H; ++k) s3 += W3b[(size_t)k*D + tid];
            sm.B3[tid] = b3b[tid] + s3;
        }
        __syncthreads();

        // y := x  (packed)
        #pragma unroll
        for (int p = 0; p < 4; ++p) {
            byA[p] = pku(xA[2*p], xA[2*p + 1]);
            byB[p] = pku(xB[2*p], xB[2*p + 1]);
        }

        for (int step = 0; step < NSTEPS; ++step) {
            const float t0 = step * dt;
            #pragma unroll 1
            for (int s = 0; s < 6; ++s) {
                const float te = t0 + dt * CC[s];

                // ======== EVAL: two samples share every weight fragment ========
                // layer 1 (K=32): C init = (b1 + te*S1)*TSCL. Output = r1 packed
                // (affine map to h folded into W2f/B2). frag ktg = L1 nt 2ktg,2ktg+1.
                f16x8 fA1[4], fB1[4];
                {
                    union { f16x8 v; uint u[4]; } ba, bb;
                    ba.u[0] = byA[0]; ba.u[1] = byA[1]; ba.u[2] = byA[2]; ba.u[3] = byA[3];
                    bb.u[0] = byB[0]; bb.u[1] = byB[1]; bb.u[2] = byB[2]; bb.u[3] = byB[3];
                    #pragma unroll
                    for (int ktg = 0; ktg < 4; ++ktg) {
                        uint da[4], db[4];
                        #pragma unroll
                        for (int h = 0; h < 2; ++h) {
                            const int nt = ktg*2 + h;
                            f16x8 wf = *(const f16x8*)&sm.W1f[(nt*64 + lane)*8];
                            f32x4 bv = *(const f32x4*)&sm.B1[nt*16 + quad*4];
                            f32x4 sv = *(const f32x4*)&sm.S1[nt*16 + quad*4];
                            f32x4 ci;
                            #pragma unroll
                            for (int r = 0; r < 4; ++r) ci[r] = fmaf(te, sv[r], bv[r]);
                            f32x4 accA = __builtin_amdgcn_mfma_f32_16x16x32_f16(wf, ba.v, ci, 0, 0, 0);
                            f32x4 accB = __builtin_amdgcn_mfma_f32_16x16x32_f16(wf, bb.v, ci, 0, 0, 0);
                            da[h*2+0] = sig_pk(accA[0], accA[1]);
                            da[h*2+1] = sig_pk(accA[2], accA[3]);
                            db[h*2+0] = sig_pk(accB[0], accB[1]);
                            db[h*2+1] = sig_pk(accB[2], accB[3]);
                        }
                        uintx4 ua = {da[0], da[1], da[2], da[3]};
                        uintx4 ub = {db[0], db[1], db[2], db[3]};
                        fA1[ktg] = __builtin_bit_cast(f16x8, ua);
                        fB1[ktg] = __builtin_bit_cast(f16x8, ub);
                    }
                }
                // layer 2 (K=128, weights -2*TSCL*W2, C-init has colsum) with
                // layer 3 FUSED (weights -2*W3, C-init has colsum): each r2
                // fragment (per ktg) feeds its 4 L3 MFMAs immediately and dies.
                float kdA[8], kdB[8];
                {
                    f32x4 a3A[2], a3B[2];
                    #pragma unroll
                    for (int n3 = 0; n3 < 2; ++n3) {
                        f32x4 c = *(const f32x4*)&sm.B3[n3*16 + quad*4];
                        a3A[n3] = c; a3B[n3] = c;
                    }
                    #pragma unroll 1
                    for (int ktg = 0; ktg < 4; ++ktg) {
                        uint da[4], db[4];
                        #pragma unroll
                        for (int h = 0; h < 2; ++h) {
                            const int nt = ktg*2 + h;
                            f32x4 c0 = *(const f32x4*)&sm.B2[nt*16 + quad*4];
                            f32x4 accA = c0, accB = c0;
                            #pragma unroll
                            for (int kt2 = 0; kt2 < 4; ++kt2) {
                                f16x8 wf = *(const f16x8*)&sm.W2f[((nt*4 + kt2)*64 + lane)*8];
                                accA = __builtin_amdgcn_mfma_f32_16x16x32_f16(wf, fA1[kt2], accA, 0, 0, 0);
                                accB = __builtin_amdgcn_mfma_f32_16x16x32_f16(wf, fB1[kt2], accB, 0, 0, 0);
                            }
                            da[h*2+0] = sig_pk(accA[0], accA[1]);
                            da[h*2+1] = sig_pk(accA[2], accA[3]);
                            db[h*2+0] = sig_pk(accB[0], accB[1]);
                            db[h*2+1] = sig_pk(accB[2], accB[3]);
                        }
                        uintx4 ua = {da[0], da[1], da[2], da[3]};
                        uintx4 ub = {db[0], db[1], db[2], db[3]};
                        f16x8 fra = __builtin_bit_cast(f16x8, ua);
                        f16x8 frb = __builtin_bit_cast(f16x8, ub);
                        #pragma unroll
                        for (int n3 = 0; n3 < 2; ++n3) {
                            f16x8 wf3 = *(const f16x8*)&sm.W3f[((n3*4 + ktg)*64 + lane)*8];
                            a3A[n3] = __builtin_amdgcn_mfma_f32_16x16x32_f16(wf3, fra, a3A[n3], 0, 0, 0);
                            a3B[n3] = __builtin_amdgcn_mfma_f32_16x16x32_f16(wf3, frb, a3B[n3], 0, 0, 0);
                        }
                    }
                    #pragma unroll
                    for (int n3 = 0; n3 < 2; ++n3)
                        #pragma unroll
                        for (int r = 0; r < 4; ++r) {
                            kdA[n3*4 + r] = a3A[n3][r];
                            kdB[n3*4 + r] = a3B[n3][r];
                        }
                }

                // ===== DOPRI combine; k1..k3 history in LDS stash, k4/k5 in
                // registers. Each thread touches only its own stash slots. =====
                switch (s) {
                case 0:
                    #pragma unroll
                    for (int j = 0; j < 4; ++j) {
                        sm.KS[0][0][j][tid] = pku(kdA[2*j], kdA[2*j+1]);
                        byA[j] = pku(fmaf(dt*0.2f, kdA[2*j],   xA[2*j]),
                                     fmaf(dt*0.2f, kdA[2*j+1], xA[2*j+1]));
                        sm.KS[0][1][j][tid] = pku(kdB[2*j], kdB[2*j+1]);
                        byB[j] = pku(fmaf(dt*0.2f, kdB[2*j],   xB[2*j]),
                                     fmaf(dt*0.2f, kdB[2*j+1], xB[2*j+1]));
                    }
                    break;
                case 1:
                    #pragma unroll
                    for (int j = 0; j < 4; ++j) {
                        uint a0 = sm.KS[0][0][j][tid];
                        sm.KS[1][0][j][tid] = pku(kdA[2*j], kdA[2*j+1]);
                        byA[j] = pku(xA[2*j]   + dt*((3.f/40.f)*lo32(a0) + (9.f/40.f)*kdA[2*j]),
                                     xA[2*j+1] + dt*((3.f/40.f)*hi32(a0) + (9.f/40.f)*kdA[2*j+1]));
                        uint b0 = sm.KS[0][1][j][tid];
                        sm.KS[1][1][j][tid] = pku(kdB[2*j], kdB[2*j+1]);
                        byB[j] = pku(xB[2*j]   + dt*((3.f/40.f)*lo32(b0) + (9.f/40.f)*kdB[2*j]),
                                     xB[2*j+1] + dt*((3.f/40.f)*hi32(b0) + (9.f/40.f)*kdB[2*j+1]));
                    }
                    break;
                case 2:
                    #pragma unroll
                    for (int j = 0; j < 4; ++j) {
                        uint a0 = sm.KS[0][0][j][tid], a1 = sm.KS[1][0][j][tid];
                        sm.KS[2][0][j][tid] = pku(kdA[2*j], kdA[2*j+1]);
                        byA[j] = pku(xA[2*j]   + dt*((44.f/45.f)*lo32(a0) - (56.f/15.f)*lo32(a1) + (32.f/9.f)*kdA[2*j]),
                                     xA[2*j+1] + dt*((44.f/45.f)*hi32(a0) - (56.f/15.f)*hi32(a1) + (32.f/9.f)*kdA[2*j+1]));
                        uint b0 = sm.KS[0][1][j][tid], b1 = sm.KS[1][1][j][tid];
                        sm.KS[2][1][j][tid] = pku(kdB[2*j], kdB[2*j+1]);
                        byB[j] = pku(xB[2*j]   + dt*((44.f/45.f)*lo32(b0) - (56.f/15.f)*lo32(b1) + (32.f/9.f)*kdB[2*j]),
                                     xB[2*j+1] + dt*((44.f/45.f)*hi32(b0) - (56.f/15.f)*hi32(b1) + (32.f/9.f)*kdB[2*j+1]));
                    }
                    break;
                case 3:
                    #pragma unroll
                    for (int j = 0; j < 4; ++j) {
                        uint a0 = sm.KS[0][0][j][tid], a1 = sm.KS[1][0][j][tid], a2 = sm.KS[2][0][j][tid];
                        k3A[j] = pku(kdA[2*j], kdA[2*j+1]);
                        byA[j] = pku(xA[2*j]   + dt*((19372.f/6561.f)*lo32(a0) - (25360.f/2187.f)*lo32(a1)
                                                   + (64448.f/6561.f)*lo32(a2) - (212.f/729.f)*kdA[2*j]),
                                     xA[2*j+1] + dt*((19372.f/6561.f)*hi32(a0) - (25360.f/2187.f)*hi32(a1)
                                                   + (64448.f/6561.f)*hi32(a2) - (212.f/729.f)*kdA[2*j+1]));
                        uint b0 = sm.KS[0][1][j][tid], b1 = sm.KS[1][1][j][tid], b2 = sm.KS[2][1][j][tid];
                        k3B[j] = pku(kdB[2*j], kdB[2*j+1]);
                        byB[j] = pku(xB[2*j]   + dt*((19372.f/6561.f)*lo32(b0) - (25360.f/2187.f)*lo32(b1)
                                                   + (64448.f/6561.f)*lo32(b2) - (212.f/729.f)*kdB[2*j]),
                                     xB[2*j+1] + dt*((19372.f/6561.f)*hi32(b0) - (25360.f/2187.f)*hi32(b1)
                                                   + (64448.f/6561.f)*hi32(b2) - (212.f/729.f)*kdB[2*j+1]));
                    }
                    break;
                case 4:
                    #pragma unroll
                    for (int j = 0; j < 4; ++j) {
                        uint a0 = sm.KS[0][0][j][tid], a1 = sm.KS[1][0][j][tid], a2 = sm.KS[2][0][j][tid];
                        k4A[j] = pku(kdA[2*j], kdA[2*j+1]);
                        byA[j] = pku(xA[2*j]   + dt*((9017.f/3168.f)*lo32(a0) - (355.f/33.f)*lo32(a1)
                                                   + (46732.f/5247.f)*lo32(a2) + (49.f/176.f)*lo32(k3A[j])
                                                   - (5103.f/18656.f)*kdA[2*j]),
                                     xA[2*j+1] + dt*((9017.f/3168.f)*hi32(a0) - (355.f/33.f)*hi32(a1)
                                                   + (46732.f/5247.f)*hi32(a2) + (49.f/176.f)*hi32(k3A[j])
                                                   - (5103.f/18656.f)*kdA[2*j+1]));
                        uint b0 = sm.KS[0][1][j][tid], b1 = sm.KS[1][1][j][tid], b2 = sm.KS[2][1][j][tid];
                        k4B[j] = pku(kdB[2*j], kdB[2*j+1]);
                        byB[j] = pku(xB[2*j]   + dt*((9017.f/3168.f)*lo32(b0) - (355.f/33.f)*lo32(b1)
                                                   + (46732.f/5247.f)*lo32(b2) + (49.f/176.f)*lo32(k3B[j])
                                                   - (5103.f/18656.f)*kdB[2*j]),
                                     xB[2*j+1] + dt*((9017.f/3168.f)*hi32(b0) - (355.f/33.f)*hi32(b1)
                                                   + (46732.f/5247.f)*hi32(b2) + (49.f/176.f)*hi32(k3B[j])
                                                   - (5103.f/18656.f)*kdB[2*j+1]));
                    }
                    break;
                default:
                    #pragma unroll
                    for (int j = 0; j < 4; ++j) {
                        uint a0 = sm.KS[0][0][j][tid], a2 = sm.KS[2][0][j][tid];
                        float xa = xA[2*j]   + dt*((35.f/384.f)*lo32(a0) + (500.f/1113.f)*lo32(a2)
                                                 + (125.f/192.f)*lo32(k3A[j]) - (2187.f/6784.f)*lo32(k4A[j])
                                                 + (11.f/84.f)*kdA[2*j]);
                        float xb = xA[2*j+1] + dt*((35.f/384.f)*hi32(a0) + (500.f/1113.f)*hi32(a2)
                                                 + (125.f/192.f)*hi32(k3A[j]) - (2187.f/6784.f)*hi32(k4A[j])
                                                 + (11.f/84.f)*kdA[2*j+1]);
                        xA[2*j] = xa; xA[2*j+1] = xb;
                        byA[j] = pku(xa, xb);
                        uint b0 = sm.KS[0][1][j][tid], b2 = sm.KS[2][1][j][tid];
                        float xc = xB[2*j]   + dt*((35.f/384.f)*lo32(b0) + (500.f/1113.f)*lo32(b2)
                                                 + (125.f/192.f)*lo32(k3B[j]) - (2187.f/6784.f)*lo32(k4B[j])
                                                 + (11.f/84.f)*kdB[2*j]);
                        float xd = xB[2*j+1] + dt*((35.f/384.f)*hi32(b0) + (500.f/1113.f)*hi32(b2)
                                                 + (125.f/192.f)*hi32(k3B[j]) - (2187.f/6784.f)*hi32(k4B[j])
                                                 + (11.f/84.f)*kdB[2*j+1]);
                        xB[2*j] = xc; xB[2*j+1] = xd;
                        byB[j] = pku(xc, xd);
                    }
                    break;
                }
            } // stages
        } // steps
    } // bijectors

    #pragma unroll
    for (int nt = 0; nt < 2; ++nt) {
        f32x4 va, vb;
        #pragma unroll
        for (int r = 0; r < 4; ++r) { va[r] = xA[nt*4 + r]; vb[r] = xB[nt*4 + r]; }
        *(f32x4*)(out + (size_t)sidxA*D + nt*16 + quad*4) = va;
        *(f32x4*)(out + (size_t)sidxB*D + nt*16 + quad*4) = vb;
    }
}

extern "C" void kernel_launch(void* const* d_in, const int* in_sizes, int n_in,
                              void* d_out, int out_size, void* d_ws, size_t ws_size,
                              hipStream_t stream) {
    (void)d_ws; (void)ws_size; (void)n_in; (void)out_size;
    const float* x  = (const float*)d_in[0];
    const float* W1 = (const float*)d_in[1];
    const float* b1 = (const float*)d_in[2];
    const float* W2 = (const float*)d_in[3];
    const float* b2 = (const float*)d_in[4];
    const float* W3 = (const float*)d_in[5];
    const float* b3 = (const float*)d_in[6];
    float* out = (float*)d_out;

    const int n = in_sizes[0] / D;          // 65536 samples
    const int grid = n / 128;               // 512 blocks (128 samples each), exact
    ffjord_mfma<<<grid, BT, 0, stream>>>(x, W1, b1, W2, b2, W3, b3, out);
}

// Round 14
// 501.037 us; speedup vs baseline: 1.1230x; 1.0339x over previous
//
#include <hip/hip_runtime.h>

#define NB 2
#define D 32
#define H 128
#define NSTEPS 8
#define BT 256

typedef _Float16 f16;
typedef _Float16 f16x2 __attribute__((ext_vector_type(2)));
typedef _Float16 f16x8 __attribute__((ext_vector_type(8)));
typedef float    f32x2 __attribute__((ext_vector_type(2)));
typedef float    f32x4 __attribute__((ext_vector_type(4)));
typedef unsigned int uint;
typedef uint uintx4 __attribute__((ext_vector_type(4)));

// Weights/biases feeding a tanh are pre-scaled by 2*log2(e) at staging time, so
// the MFMA accumulator is already v = 2*log2e*z:  tanh(z) = 1 - 2*rcp(1+2^v).
#define TSCL 2.8853900817779268f

__device__ __forceinline__ f32x2 sp2(float v) { f32x2 r; r[0] = v; r[1] = v; return r; }
__device__ __forceinline__ f32x2 fma2(f32x2 a, f32x2 b, f32x2 c) {
    return __builtin_elementwise_fma(a, b, c);   // -> v_pk_fma_f32 (CDNA packed fp32)
}

// AFFINE-FOLD (R23, kept): "1 - 2r" folded into next layer (W' = -2W,
// B' = b + colsum W); eval passes r = rcp(1+2^v) directly. Saturation exact.
// PACKED-F32 (R24): the 1+e add runs on an f32x2 pair -> v_pk_add_f32.
__device__ __forceinline__ uint sig_pk(float a, float b) {
    f32x2 e; e[0] = __builtin_amdgcn_exp2f(a); e[1] = __builtin_amdgcn_exp2f(b);
    f32x2 q = e + 1.f;
    return __builtin_bit_cast(uint, __builtin_amdgcn_cvt_pkrtz(
        __builtin_amdgcn_rcpf(q[0]), __builtin_amdgcn_rcpf(q[1])));
}
__device__ __forceinline__ uint pku(float a, float b) {
    return __builtin_bit_cast(uint, __builtin_amdgcn_cvt_pkrtz(a, b));
}
__device__ __forceinline__ f32x2 up2(uint u) {
    f16x2 h = __builtin_bit_cast(f16x2, u);
    f32x2 r; r[0] = (float)h[0]; r[1] = (float)h[1];
    return r;
}

__device__ const float CC[6] = {0.f, 0.2f, 0.3f, 0.8f, 8.f/9.f, 1.f};

// BOTTLENECK MODEL (R0..R23 measured):
//  * LADDER: 747 -> 710 (dual-sample ILP) -> 660 (L2/L3 fusion) -> 552/576
//    (R21: k1..k3 -> LDS stash, spill ELIMINATED) -> 518/526 (R23:
//    affine-fold deleted 128 fma/thread-stage).
//  * R22 setprio REGRESSED (lockstep waves, nothing to arbitrate). Reverted.
//  * Issue audit @R23: ~4570 VALU cyc/wave-stage; tanh chain ~2430 (exp2+rcp
//    trans ~8cy each — LUT R14 and batched-rcp R19 both regressed, chain is
//    minimal), DOPRI ~450, ci 64, rest unpack/moves. VALU 69.5 + MFMA 26 =
//    ~95% combined pipe issue -> op-count reduction is the only lever left.
//  * THIS ROUND (R24): packed FP32. DOPRI state/combine as f32x2 pairs via
//    __builtin_elementwise_fma -> v_pk_fma_f32 (CDNA dual-issue f32); ci as
//    f32x4 elementwise fma; tanh's 1+e add paired. ~2T->T ops per combine.
//    Worst case (no pk selection): identical scalar count, neutral.
//  * Occupancy CLOSED: 3 blocks/CU impossible (W2f 32K + KS 24.5K > 53.3K);
//    3 samples/thread re-spills. min-waves=2 + KS stash = zero-spill point.
struct __align__(16) SMem {
    f16   W1f[8 * 64 * 8];     // [nt][lane][j]      : TSCL*W1[32+phi1(q,j)][nt*16+mr]
    f16   W2f[8 * 4 * 64 * 8]; // [nt][kt][lane][j]  : -2*TSCL*W2[phi(kt,q,j)][nt*16+mr]
    f16   W3f[2 * 4 * 64 * 8]; // [nt][kt][lane][j]  : -2*W3[phi(kt,q,j)][nt*16+mr]
    float B1[H], S1[H], B2[H], B3[D];   // B1,S1 x TSCL; B2=TSCL*(b2+colsumW2); B3=b3+colsumW3
    uint  KS[3][2][4][BT];     // k1..k3 history stash [k-idx][sample][j][tid]
                               // lane-stride 4B -> conflict-free; private per
                               // thread -> NO barrier needed.
};

// phi(kt,q,j) = (2kt + j/4)*16 + q*4 + j%4 ; phi1(q,j) = (j/4)*16 + q*4 + j%4.
// Identical k-permutation on A (staged weights) and B (C-layout activations)
// -> MFMA k-sum invariant. Zero activation LDS traffic, zero shuffles.
//
// REGISTER MODEL (measured R3..R23):
//  * min-waves=2 -> VGPR=128; with the KS stash the working set FITS (zero
//    spill). min-waves=1 -> 168 regs but 1 block/CU (870us). Keep
//    flat_work_group_size(256,256) + waves_per_eu(2,2).
//  * Inner weight loops stay at unroll<=2 / unroll 1 (R4/R7: full unroll
//    -> GB-scale spill). Register arrays indexed only by unrolled vars.

// DOPRI stage combines on f32x2 pairs. smp = stash index (0=A, 1=B).
#define DOP0(smp, X2, BY, K2, K3, K4) \
    _Pragma("unroll") for (int j = 0; j < 4; ++j) { \
        sm.KS[0][smp][j][tid] = pku(K2[j][0], K2[j][1]); \
        f32x2 y = fma2(sp2(dt*0.2f), K2[j], X2[j]); \
        BY[j] = pku(y[0], y[1]); }

#define DOP1(smp, X2, BY, K2, K3, K4) \
    _Pragma("unroll") for (int j = 0; j < 4; ++j) { \
        f32x2 a0 = up2(sm.KS[0][smp][j][tid]); \
        sm.KS[1][smp][j][tid] = pku(K2[j][0], K2[j][1]); \
        f32x2 t = a0 * (3.f/40.f); \
        t = fma2(sp2(9.f/40.f), K2[j], t); \
        f32x2 y = fma2(sp2(dt), t, X2[j]); \
        BY[j] = pku(y[0], y[1]); }

#define DOP2(smp, X2, BY, K2, K3, K4) \
    _Pragma("unroll") for (int j = 0; j < 4; ++j) { \
        f32x2 a0 = up2(sm.KS[0][smp][j][tid]); \
        f32x2 a1 = up2(sm.KS[1][smp][j][tid]); \
        sm.KS[2][smp][j][tid] = pku(K2[j][0], K2[j][1]); \
        f32x2 t = a0 * (44.f/45.f); \
        t = fma2(sp2(-56.f/15.f), a1, t); \
        t = fma2(sp2(32.f/9.f), K2[j], t); \
        f32x2 y = fma2(sp2(dt), t, X2[j]); \
        BY[j] = pku(y[0], y[1]); }

#define DOP3(smp, X2, BY, K2, K3, K4) \
    _Pragma("unroll") for (int j = 0; j < 4; ++j) { \
        f32x2 a0 = up2(sm.KS[0][smp][j][tid]); \
        f32x2 a1 = up2(sm.KS[1][smp][j][tid]); \
        f32x2 a2 = up2(sm.KS[2][smp][j][tid]); \
        K3[j] = pku(K2[j][0], K2[j][1]); \
        f32x2 t = a0 * (19372.f/6561.f); \
        t = fma2(sp2(-25360.f/2187.f), a1, t); \
        t = fma2(sp2(64448.f/6561.f), a2, t); \
        t = fma2(sp2(-212.f/729.f), K2[j], t); \
        f32x2 y = fma2(sp2(dt), t, X2[j]); \
        BY[j] = pku(y[0], y[1]); }

#define DOP4(smp, X2, BY, K2, K3, K4) \
    _Pragma("unroll") for (int j = 0; j < 4; ++j) { \
        f32x2 a0 = up2(sm.KS[0][smp][j][tid]); \
        f32x2 a1 = up2(sm.KS[1][smp][j][tid]); \
        f32x2 a2 = up2(sm.KS[2][smp][j][tid]); \
        K4[j] = pku(K2[j][0], K2[j][1]); \
        f32x2 t = a0 * (9017.f/3168.f); \
        t = fma2(sp2(-355.f/33.f), a1, t); \
        t = fma2(sp2(46732.f/5247.f), a2, t); \
        t = fma2(sp2(49.f/176.f), up2(K3[j]), t); \
        t = fma2(sp2(-5103.f/18656.f), K2[j], t); \
        f32x2 y = fma2(sp2(dt), t, X2[j]); \
        BY[j] = pku(y[0], y[1]); }

#define DOP5(smp, X2, BY, K2, K3, K4) \
    _Pragma("unroll") for (int j = 0; j < 4; ++j) { \
        f32x2 a0 = up2(sm.KS[0][smp][j][tid]); \
        f32x2 a2 = up2(sm.KS[2][smp][j][tid]); \
        f32x2 t = a0 * (35.f/384.f); \
        t = fma2(sp2(500.f/1113.f), a2, t); \
        t = fma2(sp2(125.f/192.f), up2(K3[j]), t); \
        t = fma2(sp2(-2187.f/6784.f), up2(K4[j]), t); \
        t = fma2(sp2(11.f/84.f), K2[j], t); \
        X2[j] = fma2(sp2(dt), t, X2[j]); \
        BY[j] = pku(X2[j][0], X2[j][1]); }

__global__
__attribute__((amdgpu_flat_work_group_size(256, 256), amdgpu_waves_per_eu(2, 2)))
void ffjord_mfma(
    const float* __restrict__ x_in,
    const float* __restrict__ W1, const float* __restrict__ b1,
    const float* __restrict__ W2, const float* __restrict__ b2,
    const float* __restrict__ W3, const float* __restrict__ b3,
    float* __restrict__ out)
{
    __shared__ SMem sm;

    const int tid  = threadIdx.x;
    const int lane = tid & 63;
    const int mrow = lane & 15;      // my sample within the wave tile
    const int quad = lane >> 4;      // k/feature quad
    const int wid  = tid >> 6;
    // Two samples per thread: A and B tiles are independent 16-sample MFMA
    // B-fragments sharing every weight fragment / C-init.
    const int sidxA = blockIdx.x * 128 + wid * 32 + mrow;
    const int sidxB = sidxA + 16;

    f32x2 xA2[4], xB2[4];                   // state pairs (feature 2j, 2j+1)
    uint  k3A[4], k4A[4], k3B[4], k4B[4];   // k4,k5 history (hot, registers)
    uint  byA[4], byB[4];

    #pragma unroll
    for (int nt = 0; nt < 2; ++nt) {
        f32x4 va = *(const f32x4*)(x_in + (size_t)sidxA*D + nt*16 + quad*4);
        f32x4 vb = *(const f32x4*)(x_in + (size_t)sidxB*D + nt*16 + quad*4);
        xA2[nt*2+0][0] = va[0]; xA2[nt*2+0][1] = va[1];
        xA2[nt*2+1][0] = va[2]; xA2[nt*2+1][1] = va[3];
        xB2[nt*2+0][0] = vb[0]; xB2[nt*2+0][1] = vb[1];
        xB2[nt*2+1][0] = vb[2]; xB2[nt*2+1][1] = vb[3];
    }

    const float dt = 0.125f;

    for (int bij = 0; bij < NB; ++bij) {
        const float* W1b = W1 + (size_t)bij * 2*D*H;
        const float* b1b = b1 + bij*H;
        const float* W2b = W2 + (size_t)bij * H*H;
        const float* b2b = b2 + bij*H;
        const float* W3b = W3 + (size_t)bij * H*D;
        const float* b3b = b3 + bij*D;

        __syncthreads();  // prior bijector done reading weights
        // ---- stage weights: fragment-order, k-permuted, f16, prescaled ----
        #pragma unroll 1
        for (int g = tid; g < 8*64; g += BT) {               // W1f (x TSCL)
            int nt = g >> 6, ln = g & 63, q = (ln >> 4) & 3, mr = ln & 15;
            f16 tmp[8];
            #pragma unroll
            for (int j = 0; j < 8; ++j) {
                int feat = ((j >> 2) << 4) + q*4 + (j & 3);  // phi1
                tmp[j] = (f16)(W1b[(size_t)(D + feat)*H + nt*16 + mr] * TSCL);
            }
            *(f16x8*)&sm.W1f[(size_t)g * 8] = *(f16x8*)tmp;
        }
        #pragma unroll 1
        for (int g = tid; g < 8*4*64; g += BT) {             // W2f (x -2*TSCL, affine-fold)
            int nt = g >> 8, kt = (g >> 6) & 3, ln = g & 63, q = (ln >> 4) & 3, mr = ln & 15;
            f16 tmp[8];
            #pragma unroll
            for (int j = 0; j < 8; ++j) {
                int feat = (2*kt + (j >> 2))*16 + q*4 + (j & 3);  // phi
                tmp[j] = (f16)(W2b[(size_t)feat*H + nt*16 + mr] * (-2.f * TSCL));
            }
            *(f16x8*)&sm.W2f[(size_t)g * 8] = *(f16x8*)tmp;
        }
        #pragma unroll 1
        for (int g = tid; g < 2*4*64; g += BT) {             // W3f (x -2, affine-fold)
            int nt = g >> 8, kt = (g >> 6) & 3, ln = g & 63, q = (ln >> 4) & 3, mr = ln & 15;
            f16 tmp[8];
            #pragma unroll
            for (int j = 0; j < 8; ++j) {
                int feat = (2*kt + (j >> 2))*16 + q*4 + (j & 3);  // phi
                tmp[j] = (f16)(W3b[(size_t)feat*D + nt*16 + mr] * -2.f);
            }
            *(f16x8*)&sm.W3f[(size_t)g * 8] = *(f16x8*)tmp;
        }
        #pragma unroll 1
        for (int n = tid; n < H; n += BT) {                  // biases + fold sums
            float s = 0.f;                                   // t-concat fold (x TSCL)
            for (int i = 0; i < D; ++i) s += W1b[(size_t)i*H + n];
            float s2 = 0.f;                                  // affine-fold colsum W2
            for (int k = 0; k < H; ++k) s2 += W2b[(size_t)k*H + n];
            sm.S1[n] = s * TSCL;
            sm.B1[n] = b1b[n] * TSCL;
            sm.B2[n] = (b2b[n] + s2) * TSCL;
        }
        if (tid < D) {                                       // affine-fold colsum W3
            float s3 = 0.f;
            for (int k = 0; k < H; ++k) s3 += W3b[(size_t)k*D + tid];
            sm.B3[tid] = b3b[tid] + s3;
        }
        __syncthreads();

        // y := x  (packed)
        #pragma unroll
        for (int p = 0; p < 4; ++p) {
            byA[p] = pku(xA2[p][0], xA2[p][1]);
            byB[p] = pku(xB2[p][0], xB2[p][1]);
        }

        for (int step = 0; step < NSTEPS; ++step) {
            const float t0 = step * dt;
            #pragma unroll 1
            for (int s = 0; s < 6; ++s) {
                const float te = t0 + dt * CC[s];

                // ======== EVAL: two samples share every weight fragment ========
                // layer 1 (K=32): C init = (b1 + te*S1)*TSCL. Output = r1 packed
                // (affine map to h folded into W2f/B2). frag ktg = L1 nt 2ktg,2ktg+1.
                f16x8 fA1[4], fB1[4];
                {
                    union { f16x8 v; uint u[4]; } ba, bb;
                    ba.u[0] = byA[0]; ba.u[1] = byA[1]; ba.u[2] = byA[2]; ba.u[3] = byA[3];
                    bb.u[0] = byB[0]; bb.u[1] = byB[1]; bb.u[2] = byB[2]; bb.u[3] = byB[3];
                    #pragma unroll
                    for (int ktg = 0; ktg < 4; ++ktg) {
                        uint da[4], db[4];
                        #pragma unroll
                        for (int h = 0; h < 2; ++h) {
                            const int nt = ktg*2 + h;
                            f16x8 wf = *(const f16x8*)&sm.W1f[(nt*64 + lane)*8];
                            f32x4 bv = *(const f32x4*)&sm.B1[nt*16 + quad*4];
                            f32x4 sv = *(const f32x4*)&sm.S1[nt*16 + quad*4];
                            f32x4 te4; te4[0] = te; te4[1] = te; te4[2] = te; te4[3] = te;
                            f32x4 ci = __builtin_elementwise_fma(te4, sv, bv);  // v_pk_fma_f32 x2
                            f32x4 accA = __builtin_amdgcn_mfma_f32_16x16x32_f16(wf, ba.v, ci, 0, 0, 0);
                            f32x4 accB = __builtin_amdgcn_mfma_f32_16x16x32_f16(wf, bb.v, ci, 0, 0, 0);
                            da[h*2+0] = sig_pk(accA[0], accA[1]);
                            da[h*2+1] = sig_pk(accA[2], accA[3]);
                            db[h*2+0] = sig_pk(accB[0], accB[1]);
                            db[h*2+1] = sig_pk(accB[2], accB[3]);
                        }
                        uintx4 ua = {da[0], da[1], da[2], da[3]};
                        uintx4 ub = {db[0], db[1], db[2], db[3]};
                        fA1[ktg] = __builtin_bit_cast(f16x8, ua);
                        fB1[ktg] = __builtin_bit_cast(f16x8, ub);
                    }
                }
                // layer 2 (K=128, weights -2*TSCL*W2, C-init has colsum) with
                // layer 3 FUSED (weights -2*W3, C-init has colsum): each r2
                // fragment (per ktg) feeds its 4 L3 MFMAs immediately and dies.
                f32x2 kdA2[4], kdB2[4];
                {
                    f32x4 a3A[2], a3B[2];
                    #pragma unroll
                    for (int n3 = 0; n3 < 2; ++n3) {
                        f32x4 c = *(const f32x4*)&sm.B3[n3*16 + quad*4];
                        a3A[n3] = c; a3B[n3] = c;
                    }
                    #pragma unroll 1
                    for (int ktg = 0; ktg < 4; ++ktg) {
                        uint da[4], db[4];
                        #pragma unroll
                        for (int h = 0; h < 2; ++h) {
                            const int nt = ktg*2 + h;
                            f32x4 c0 = *(const f32x4*)&sm.B2[nt*16 + quad*4];
                            f32x4 accA = c0, accB = c0;
                            #pragma unroll
                            for (int kt2 = 0; kt2 < 4; ++kt2) {
                                f16x8 wf = *(const f16x8*)&sm.W2f[((nt*4 + kt2)*64 + lane)*8];
                                accA = __builtin_amdgcn_mfma_f32_16x16x32_f16(wf, fA1[kt2], accA, 0, 0, 0);
                                accB = __builtin_amdgcn_mfma_f32_16x16x32_f16(wf, fB1[kt2], accB, 0, 0, 0);
                            }
                            da[h*2+0] = sig_pk(accA[0], accA[1]);
                            da[h*2+1] = sig_pk(accA[2], accA[3]);
                            db[h*2+0] = sig_pk(accB[0], accB[1]);
                            db[h*2+1] = sig_pk(accB[2], accB[3]);
                        }
                        uintx4 ua = {da[0], da[1], da[2], da[3]};
                        uintx4 ub = {db[0], db[1], db[2], db[3]};
                        f16x8 fra = __builtin_bit_cast(f16x8, ua);
                        f16x8 frb = __builtin_bit_cast(f16x8, ub);
                        #pragma unroll
                        for (int n3 = 0; n3 < 2; ++n3) {
                            f16x8 wf3 = *(const f16x8*)&sm.W3f[((n3*4 + ktg)*64 + lane)*8];
                            a3A[n3] = __builtin_amdgcn_mfma_f32_16x16x32_f16(wf3, fra, a3A[n3], 0, 0, 0);
                            a3B[n3] = __builtin_amdgcn_mfma_f32_16x16x32_f16(wf3, frb, a3B[n3], 0, 0, 0);
                        }
                    }
                    #pragma unroll
                    for (int n3 = 0; n3 < 2; ++n3) {
                        kdA2[n3*2+0][0] = a3A[n3][0]; kdA2[n3*2+0][1] = a3A[n3][1];
                        kdA2[n3*2+1][0] = a3A[n3][2]; kdA2[n3*2+1][1] = a3A[n3][3];
                        kdB2[n3*2+0][0] = a3B[n3][0]; kdB2[n3*2+0][1] = a3B[n3][1];
                        kdB2[n3*2+1][0] = a3B[n3][2]; kdB2[n3*2+1][1] = a3B[n3][3];
                    }
                }

                // ===== DOPRI combine on f32x2 pairs (v_pk_fma_f32); k1..k3 in
                // LDS stash, k4/k5 in registers. Thread-private slots, no barrier.
                switch (s) {
                case 0:  DOP0(0, xA2, byA, kdA2, k3A, k4A) DOP0(1, xB2, byB, kdB2, k3B, k4B) break;
                case 1:  DOP1(0, xA2, byA, kdA2, k3A, k4A) DOP1(1, xB2, byB, kdB2, k3B, k4B) break;
                case 2:  DOP2(0, xA2, byA, kdA2, k3A, k4A) DOP2(1, xB2, byB, kdB2, k3B, k4B) break;
                case 3:  DOP3(0, xA2, byA, kdA2, k3A, k4A) DOP3(1, xB2, byB, kdB2, k3B, k4B) break;
                case 4:  DOP4(0, xA2, byA, kdA2, k3A, k4A) DOP4(1, xB2, byB, kdB2, k3B, k4B) break;
                default: DOP5(0, xA2, byA, kdA2, k3A, k4A) DOP5(1, xB2, byB, kdB2, k3B, k4B) break;
                }
            } // stages
        } // steps
    } // bijectors

    #pragma unroll
    for (int nt = 0; nt < 2; ++nt) {
        f32x4 va, vb;
        va[0] = xA2[nt*2+0][0]; va[1] = xA2[nt*2+0][1];
        va[2] = xA2[nt*2+1][0]; va[3] = xA2[nt*2+1][1];
        vb[0] = xB2[nt*2+0][0]; vb[1] = xB2[nt*2+0][1];
        vb[2] = xB2[nt*2+1][0]; vb[3] = xB2[nt*2+1][1];
        *(f32x4*)(out + (size_t)sidxA*D + nt*16 + quad*4) = va;
        *(f32x4*)(out + (size_t)sidxB*D + nt*16 + quad*4) = vb;
    }
}

extern "C" void kernel_launch(void* const* d_in, const int* in_sizes, int n_in,
                              void* d_out, int out_size, void* d_ws, size_t ws_size,
                              hipStream_t stream) {
    (void)d_ws; (void)ws_size; (void)n_in; (void)out_size;
    const float* x  = (const float*)d_in[0];
    const float* W1 = (const float*)d_in[1];
    const float* b1 = (const float*)d_in[2];
    const float* W2 = (const float*)d_in[3];
    const float* b2 = (const float*)d_in[4];
    const float* W3 = (const float*)d_in[5];
    const float* b3 = (const float*)d_in[6];
    float* out = (float*)d_out;

    const int n = in_sizes[0] / D;          // 65536 samples
    const int grid = n / 128;               // 512 blocks (128 samples each), exact
    ffjord_mfma<<<grid, BT, 0, stream>>>(x, W1, b1, W2, b2, W3, b3, out);
}